// Round 6
// baseline (1248.885 us; speedup 1.0000x reference)
//
#include <hip/hip_runtime.h>
#include <math.h>

#define NM 40962
#define NG 200000
#define NE 600000

typedef unsigned short u16;
typedef unsigned int u32;
typedef __attribute__((ext_vector_type(8))) short short8;
typedef __attribute__((ext_vector_type(4))) float f32x4;

// Packed bf16 W^T blobs in static device memory.
#define OFF_WE 0
#define OFF_WS 16384
#define OFF_WD 32768
#define OFF_W1 49152
#define OFF_W0 65536
#define OFF_WN1 98304
__device__ u16 g_wp[114688];  // 224 KB

__device__ __forceinline__ u32 f2bf(float f) {
  u32 u = __float_as_uint(f);
  return (u + 0x7FFFu + ((u >> 16) & 1u)) >> 16;  // RNE
}
__device__ __forceinline__ float bfl(u32 h) { return __uint_as_float(h << 16); }
__device__ __forceinline__ float bsel(u32 w, int hiHalf) {
  return hiHalf ? __uint_as_float(w & 0xFFFF0000u) : __uint_as_float(w << 16);
}
__device__ __forceinline__ float silu_f(float x) { return x / (1.f + __expf(-x)); }

#define MFMA16(a, b, c) __builtin_amdgcn_mfma_f32_16x16x32_bf16(a, b, c, 0, 0, 0)

// pack 8 f32 into bf16 hi + bf16 lo-residual frags (fp32-accurate A)
__device__ __forceinline__ void pk8(const float4& a, const float4& b, short8& hi,
                                    short8& lo) {
  float f[8] = {a.x, a.y, a.z, a.w, b.x, b.y, b.z, b.w};
#pragma unroll
  for (int j = 0; j < 8; ++j) {
    u32 h = f2bf(f[j]);
    hi[j] = (short)h;
    lo[j] = (short)f2bf(f[j] - bfl(h));
  }
}

template <int K>
__device__ __forceinline__ short8 bfrag(const u16* __restrict__ Wp, int n, int k0) {
  return *(const short8*)(Wp + (size_t)n * K + k0);
}

// ---- fused prep: pack all 6 weight mats fp32 [K][128] -> g_wp bf16 [n][K] ----
__global__ void prep_all(const float* __restrict__ We, const float* __restrict__ Ws,
                         const float* __restrict__ Wd, const float* __restrict__ W1e,
                         const float* __restrict__ Wn0, const float* __restrict__ Wn1) {
  for (int i = blockIdx.x * blockDim.x + threadIdx.x; i < 114688;
       i += gridDim.x * blockDim.x) {
    const float* W;
    int loc, kb;
    if (i < 16384)       { W = We;  loc = i;         kb = 7; }
    else if (i < 32768)  { W = Ws;  loc = i - 16384; kb = 7; }
    else if (i < 49152)  { W = Wd;  loc = i - 32768; kb = 7; }
    else if (i < 65536)  { W = W1e; loc = i - 49152; kb = 7; }
    else if (i < 98304)  { W = Wn0; loc = i - 65536; kb = 8; }
    else                 { W = Wn1; loc = i - 98304; kb = 7; }
    int n = loc >> kb, k = loc & ((1 << kb) - 1);
    g_wp[i] = (u16)f2bf(W[(size_t)k * 128 + n]);
  }
}

// ---- fused proj (mesh->PS, grid->PD) M=32/wave, cross-tile A-prefetch,
//      agg zeroing folded in ----
__device__ __forceinline__ void proj_src(int t, const float* mesh, const float* gridf,
                                         const float*& X, int& n0, int& nrows) {
  const int TM = (NM + 31) / 32;  // 1281
  if (t < TM) { X = mesh;  n0 = t * 32;        nrows = NM; }
  else        { X = gridf; n0 = (t - TM) * 32; nrows = NG; }
}

__global__ __launch_bounds__(256) void proj_kernel(const float* __restrict__ mesh,
                                                   const float* __restrict__ gridf,
                                                   uint4* __restrict__ PS,
                                                   uint4* __restrict__ PD,
                                                   float* __restrict__ agg) {
  const int TM = (NM + 31) / 32;  // 1281
  const int TG = NG / 32;         // 6250
  const int T = TM + TG;
  const int lane = threadIdx.x & 63, wv = threadIdx.x >> 6;
  const int g = lane >> 4, c = lane & 15;
  const int nw = gridDim.x * 4;
  int t0 = blockIdx.x * 4 + wv;
  if (t0 >= T) return;
  float4 av[2][4][2];
  {  // prologue A
    const float* X; int n0, nrows;
    proj_src(t0, mesh, gridf, X, n0, nrows);
#pragma unroll
    for (int mt = 0; mt < 2; ++mt)
#pragma unroll
      for (int kt = 0; kt < 4; ++kt) {
        int row = n0 + 16 * mt + c;
        if (row >= nrows) row = nrows - 1;
        const float4* p = (const float4*)(X + (size_t)row * 128 + 32 * kt + 8 * g);
        av[mt][kt][0] = p[0];
        av[mt][kt][1] = p[1];
      }
  }
  for (int t = t0; t < T; t += nw) {
    const float* X; int n0, nrows;
    proj_src(t, mesh, gridf, X, n0, nrows);
    const u16* Wp = (t < TM) ? (g_wp + OFF_WS) : (g_wp + OFF_WD);
    uint4* O = (t < TM) ? PS : PD;
    int zero = (t >= TM);
    f32x4 acc[2][8];
#pragma unroll
    for (int mt = 0; mt < 2; ++mt)
#pragma unroll
      for (int nt = 0; nt < 8; ++nt) {
        f32x4 z = {0.f, 0.f, 0.f, 0.f};
        acc[mt][nt] = z;
      }
#pragma unroll
    for (int kt = 0; kt < 4; ++kt) {
      short8 ah[2], al[2];
#pragma unroll
      for (int mt = 0; mt < 2; ++mt) pk8(av[mt][kt][0], av[mt][kt][1], ah[mt], al[mt]);
#pragma unroll
      for (int nt = 0; nt < 8; ++nt) {
        short8 b = bfrag<128>(Wp, 16 * nt + c, 32 * kt + 8 * g);
#pragma unroll
        for (int mt = 0; mt < 2; ++mt) {
          acc[mt][nt] = MFMA16(ah[mt], b, acc[mt][nt]);
          acc[mt][nt] = MFMA16(al[mt], b, acc[mt][nt]);
        }
      }
    }
    {  // cross-tile A prefetch (same regs; av dead after kt loop)
      int tn = t + nw;
      if (tn < T) {
        const float* Xn; int n0n, nrn;
        proj_src(tn, mesh, gridf, Xn, n0n, nrn);
#pragma unroll
        for (int mt = 0; mt < 2; ++mt)
#pragma unroll
          for (int kt = 0; kt < 4; ++kt) {
            int row = n0n + 16 * mt + c;
            if (row >= nrn) row = nrn - 1;
            const float4* p = (const float4*)(Xn + (size_t)row * 128 + 32 * kt + 8 * g);
            av[mt][kt][0] = p[0];
            av[mt][kt][1] = p[1];
          }
      }
    }
#pragma unroll
    for (int mt = 0; mt < 2; ++mt)
#pragma unroll
      for (int r = 0; r < 4; ++r) {
        int row = n0 + 16 * mt + 4 * g + r;
        if (row < nrows) {
          uint4 v;
          v.x = f2bf(acc[mt][0][r]) | (f2bf(acc[mt][1][r]) << 16);
          v.y = f2bf(acc[mt][2][r]) | (f2bf(acc[mt][3][r]) << 16);
          v.z = f2bf(acc[mt][4][r]) | (f2bf(acc[mt][5][r]) << 16);
          v.w = f2bf(acc[mt][6][r]) | (f2bf(acc[mt][7][r]) << 16);
          O[(size_t)row * 16 + c] = v;
          if (zero) {  // agg zeroing folded (replaces hipMemsetAsync)
            float4 z = {0.f, 0.f, 0.f, 0.f};
            float4* ap = (float4*)(agg + (size_t)row * 128 + c * 8);
            ap[0] = z;
            ap[1] = z;
          }
        }
      }
  }
}

// ---- edge (M=32/wave): silu(m2g@We + PS[src] + PD[dst] + b0) @ W1e -> LN -> atomics
//      cross-tile A-prefetch; gather consumption deferred post-GEMM1 ----
__global__ __launch_bounds__(256) void edge_kernel(
    const float* __restrict__ m2g, const uint4* __restrict__ PS,
    const uint4* __restrict__ PD, const int* __restrict__ src_idx,
    const int* __restrict__ dst_idx, const float* __restrict__ b0,
    const float* __restrict__ b1e, const float* __restrict__ ge,
    const float* __restrict__ be, float* __restrict__ agg) {
  const u16* WpE = g_wp + OFF_WE;
  const u16* Wp1 = g_wp + OFF_W1;
  __shared__ __align__(16) u16 hbh[4][32][128];  // hi plane, 32KB
  __shared__ __align__(16) u16 hbl[4][32][128];  // lo plane, 32KB
  const int lane = threadIdx.x & 63, wv = threadIdx.x >> 6;
  const int g = lane >> 4, c = lane & 15;
  float b0p[8];
#pragma unroll
  for (int nt = 0; nt < 8; ++nt) b0p[nt] = b0[16 * nt + c];
  const int nw = gridDim.x * 4;
  const int T = NE / 32;
  int t0 = blockIdx.x * 4 + wv;
  if (t0 >= T) return;
  float4 av[2][4][2];
  {  // prologue A
    const int e0 = t0 * 32;
#pragma unroll
    for (int mt = 0; mt < 2; ++mt)
#pragma unroll
      for (int kt = 0; kt < 4; ++kt) {
        const float4* p =
            (const float4*)(m2g + (size_t)(e0 + 16 * mt + c) * 128 + 32 * kt + 8 * g);
        av[mt][kt][0] = p[0];
        av[mt][kt][1] = p[1];
      }
  }
  for (int t = t0; t < T; t += nw) {
    const int e0 = t * 32;
    // gathers issued at top; consumed after GEMM1 (covered by MFMA)
    int dd[2][4];
    uint4 ps[2][4], pd[2][4];
#pragma unroll
    for (int mt = 0; mt < 2; ++mt)
#pragma unroll
      for (int r = 0; r < 4; ++r) {
        int e = e0 + 16 * mt + 4 * g + r;
        int s = src_idx[e];
        int d = dst_idx[e];
        dd[mt][r] = d;
        ps[mt][r] = PS[(size_t)s * 16 + c];
        pd[mt][r] = PD[(size_t)d * 16 + c];
      }
    // GEMM1 from zero (A already resident from prefetch)
    f32x4 acc[2][8];
#pragma unroll
    for (int mt = 0; mt < 2; ++mt)
#pragma unroll
      for (int nt = 0; nt < 8; ++nt) {
        f32x4 z = {0.f, 0.f, 0.f, 0.f};
        acc[mt][nt] = z;
      }
#pragma unroll
    for (int kt = 0; kt < 4; ++kt) {
      short8 ah[2], al[2];
#pragma unroll
      for (int mt = 0; mt < 2; ++mt) pk8(av[mt][kt][0], av[mt][kt][1], ah[mt], al[mt]);
#pragma unroll
      for (int nt = 0; nt < 8; ++nt) {
        short8 b = bfrag<128>(WpE, 16 * nt + c, 32 * kt + 8 * g);
#pragma unroll
        for (int mt = 0; mt < 2; ++mt) {
          acc[mt][nt] = MFMA16(ah[mt], b, acc[mt][nt]);
          acc[mt][nt] = MFMA16(al[mt], b, acc[mt][nt]);
        }
      }
    }
    {  // cross-tile A prefetch: issue now, consumed next iteration.
       // Latency hidden under silu+GEMM2+LN+atomics (~4k cy).
      int tn = t + nw;
      if (tn < T) {
        const int en = tn * 32;
#pragma unroll
        for (int mt = 0; mt < 2; ++mt)
#pragma unroll
          for (int kt = 0; kt < 4; ++kt) {
            const float4* p =
                (const float4*)(m2g + (size_t)(en + 16 * mt + c) * 128 + 32 * kt + 8 * g);
            av[mt][kt][0] = p[0];
            av[mt][kt][1] = p[1];
          }
      }
    }
    // deferred add of b0 + ps + pd (first consumption of the gathers)
#pragma unroll
    for (int mt = 0; mt < 2; ++mt)
#pragma unroll
      for (int nt = 0; nt < 8; ++nt)
#pragma unroll
        for (int r = 0; r < 4; ++r) {
          u32 pw = ((const u32*)&ps[mt][r])[nt >> 1];
          u32 qw = ((const u32*)&pd[mt][r])[nt >> 1];
          acc[mt][nt][r] += b0p[nt] + bsel(pw, nt & 1) + bsel(qw, nt & 1);
        }
    // silu -> hi/lo planes (XOR-swizzled)
#pragma unroll
    for (int mt = 0; mt < 2; ++mt)
#pragma unroll
      for (int r = 0; r < 4; ++r) {
        int row = 16 * mt + 4 * g + r;
        int sw = (row & 7) << 3;
#pragma unroll
        for (int nt = 0; nt < 8; ++nt) {
          float h = silu_f(acc[mt][nt][r]);
          u32 hb = f2bf(h);
          u32 lb = f2bf(h - bfl(hb));
          int idx = (16 * nt + c) ^ sw;
          hbh[wv][row][idx] = (u16)hb;
          hbl[wv][row][idx] = (u16)lb;
        }
      }
    // GEMM2: acc2 = b1e + h @ W1e (in-wave LDS transpose, no barrier needed)
    f32x4 acc2[2][8];
    {
      float b1p[8];
#pragma unroll
      for (int nt = 0; nt < 8; ++nt) b1p[nt] = b1e[16 * nt + c];
#pragma unroll
      for (int mt = 0; mt < 2; ++mt)
#pragma unroll
        for (int nt = 0; nt < 8; ++nt) {
          f32x4 a = {b1p[nt], b1p[nt], b1p[nt], b1p[nt]};
          acc2[mt][nt] = a;
        }
    }
#pragma unroll
    for (int kt = 0; kt < 4; ++kt) {
      short8 ah[2], al[2];
#pragma unroll
      for (int mt = 0; mt < 2; ++mt) {
        int row = 16 * mt + c;
        int idx = (32 * kt + 8 * g) ^ ((c & 7) << 3);
        ah[mt] = *(const short8*)&hbh[wv][row][idx];
        al[mt] = *(const short8*)&hbl[wv][row][idx];
      }
#pragma unroll
      for (int nt = 0; nt < 8; ++nt) {
        short8 b = bfrag<128>(Wp1, 16 * nt + c, 32 * kt + 8 * g);
#pragma unroll
        for (int mt = 0; mt < 2; ++mt) {
          acc2[mt][nt] = MFMA16(ah[mt], b, acc2[mt][nt]);
          acc2[mt][nt] = MFMA16(al[mt], b, acc2[mt][nt]);
        }
      }
    }
    // LN (16-lane shuffle reduce)
    float gep[8], bep[8];
#pragma unroll
    for (int nt = 0; nt < 8; ++nt) {
      gep[nt] = ge[16 * nt + c];
      bep[nt] = be[16 * nt + c];
    }
#pragma unroll
    for (int mt = 0; mt < 2; ++mt) {
#pragma unroll
      for (int r = 0; r < 4; ++r) {
        float sm = 0.f, sq = 0.f;
#pragma unroll
        for (int nt = 0; nt < 8; ++nt) {
          float v = acc2[mt][nt][r];
          sm += v;
          sq += v * v;
        }
#pragma unroll
        for (int m = 1; m < 16; m <<= 1) {
          sm += __shfl_xor(sm, m, 64);
          sq += __shfl_xor(sq, m, 64);
        }
        float mu = sm * (1.f / 128.f);
        float var = sq * (1.f / 128.f) - mu * mu;
        float rs = rsqrtf(var + 1e-5f);
#pragma unroll
        for (int nt = 0; nt < 8; ++nt)
          acc2[mt][nt][r] = (acc2[mt][nt][r] - mu) * rs * gep[nt] + bep[nt];
      }
      // dst-run-merged atomics (dst sorted -> adjacent duplicates merge)
#pragma unroll
      for (int nt = 0; nt < 8; ++nt) {
        float a = acc2[mt][nt][0];
        int dp = dd[mt][0];
#pragma unroll
        for (int r = 1; r < 4; ++r) {
          if (dd[mt][r] == dp) {
            a += acc2[mt][nt][r];
          } else {
            atomicAdd(agg + (size_t)dp * 128 + 16 * nt + c, a);
            a = acc2[mt][nt][r];
            dp = dd[mt][r];
          }
        }
        atomicAdd(agg + (size_t)dp * 128 + 16 * nt + c, a);
      }
    }
  }
}

// ---- node (fused A+B, M=32/wave, cross-tile A-prefetch) ----
__global__ __launch_bounds__(256) void node_kernel(
    const float* __restrict__ gridf, const float* __restrict__ agg,
    const float* __restrict__ bn0, const float* __restrict__ bn1,
    const float* __restrict__ gn, const float* __restrict__ bnv,
    float* __restrict__ out) {
  const u16* Wp0 = g_wp + OFF_W0;
  const u16* Wp1 = g_wp + OFF_WN1;
  __shared__ __align__(16) u16 nbuf[4][32][128];  // hn bf16, 32 KB/block
  const int lane = threadIdx.x & 63, wv = threadIdx.x >> 6;
  const int g = lane >> 4, c = lane & 15;
  float b0p[8], b1p[8];
#pragma unroll
  for (int nt = 0; nt < 8; ++nt) {
    b0p[nt] = bn0[16 * nt + c];
    b1p[nt] = bn1[16 * nt + c];
  }
  const int nw = gridDim.x * 4;
  const int T = NG / 32;
  int t0 = blockIdx.x * 4 + wv;
  if (t0 >= T) return;
  float4 av[2][8][2];  // [mt][kt][half]: grid rows kt<4, agg rows kt>=4
  {  // prologue A
    const int n0 = t0 * 32;
#pragma unroll
    for (int mt = 0; mt < 2; ++mt)
#pragma unroll
      for (int kt = 0; kt < 8; ++kt) {
        const float* src = (kt < 4) ? gridf : agg;
        const float4* p = (const float4*)(src + (size_t)(n0 + 16 * mt + c) * 128 +
                                          (kt & 3) * 32 + 8 * g);
        av[mt][kt][0] = p[0];
        av[mt][kt][1] = p[1];
      }
  }
  for (int t = t0; t < T; t += nw) {
    const int n0 = t * 32;
    f32x4 acc[2][8];
#pragma unroll
    for (int mt = 0; mt < 2; ++mt)
#pragma unroll
      for (int nt = 0; nt < 8; ++nt) {
        f32x4 a = {b0p[nt], b0p[nt], b0p[nt], b0p[nt]};
        acc[mt][nt] = a;
      }
#pragma unroll
    for (int kt = 0; kt < 8; ++kt) {
      short8 ah[2], al[2];
#pragma unroll
      for (int mt = 0; mt < 2; ++mt) pk8(av[mt][kt][0], av[mt][kt][1], ah[mt], al[mt]);
#pragma unroll
      for (int nt = 0; nt < 8; ++nt) {
        short8 b = bfrag<256>(Wp0, 16 * nt + c, 32 * kt + 8 * g);
#pragma unroll
        for (int mt = 0; mt < 2; ++mt) {
          acc[mt][nt] = MFMA16(ah[mt], b, acc[mt][nt]);
          acc[mt][nt] = MFMA16(al[mt], b, acc[mt][nt]);
        }
      }
    }
    {  // cross-tile A prefetch
      int tn = t + nw;
      if (tn < T) {
        const int n0n = tn * 32;
#pragma unroll
        for (int mt = 0; mt < 2; ++mt)
#pragma unroll
          for (int kt = 0; kt < 8; ++kt) {
            const float* src = (kt < 4) ? gridf : agg;
            const float4* p = (const float4*)(src + (size_t)(n0n + 16 * mt + c) * 128 +
                                              (kt & 3) * 32 + 8 * g);
            av[mt][kt][0] = p[0];
            av[mt][kt][1] = p[1];
          }
      }
    }
    // hn -> LDS (bf16)
#pragma unroll
    for (int mt = 0; mt < 2; ++mt)
#pragma unroll
      for (int r = 0; r < 4; ++r) {
        int row = 16 * mt + 4 * g + r;
        int sw = (row & 7) << 3;
#pragma unroll
        for (int nt = 0; nt < 8; ++nt)
          nbuf[wv][row][(16 * nt + c) ^ sw] = (u16)f2bf(silu_f(acc[mt][nt][r]));
      }
    f32x4 acc2[2][8];
#pragma unroll
    for (int mt = 0; mt < 2; ++mt)
#pragma unroll
      for (int nt = 0; nt < 8; ++nt) {
        f32x4 a = {b1p[nt], b1p[nt], b1p[nt], b1p[nt]};
        acc2[mt][nt] = a;
      }
#pragma unroll
    for (int kt = 0; kt < 4; ++kt) {
      short8 ah[2];
#pragma unroll
      for (int mt = 0; mt < 2; ++mt) {
        int row = 16 * mt + c;
        ah[mt] = *(const short8*)&nbuf[wv][row][(32 * kt + 8 * g) ^ ((c & 7) << 3)];
      }
#pragma unroll
      for (int nt = 0; nt < 8; ++nt) {
        short8 b = bfrag<128>(Wp1, 16 * nt + c, 32 * kt + 8 * g);
#pragma unroll
        for (int mt = 0; mt < 2; ++mt) acc2[mt][nt] = MFMA16(ah[mt], b, acc2[mt][nt]);
      }
    }
    // LN + residual + store
    float gp[8], bp[8];
#pragma unroll
    for (int nt = 0; nt < 8; ++nt) {
      gp[nt] = gn[16 * nt + c];
      bp[nt] = bnv[16 * nt + c];
    }
#pragma unroll
    for (int mt = 0; mt < 2; ++mt)
#pragma unroll
      for (int r = 0; r < 4; ++r) {
        float sm = 0.f, sq = 0.f;
#pragma unroll
        for (int nt = 0; nt < 8; ++nt) {
          float v = acc2[mt][nt][r];
          sm += v;
          sq += v * v;
        }
#pragma unroll
        for (int m = 1; m < 16; m <<= 1) {
          sm += __shfl_xor(sm, m, 64);
          sq += __shfl_xor(sq, m, 64);
        }
        float mu = sm * (1.f / 128.f);
        float var = sq * (1.f / 128.f) - mu * mu;
        float rs = rsqrtf(var + 1e-5f);
        int row = n0 + 16 * mt + 4 * g + r;
#pragma unroll
        for (int nt = 0; nt < 8; ++nt) {
          size_t o = (size_t)row * 128 + 16 * nt + c;
          out[o] = (acc2[mt][nt][r] - mu) * rs * gp[nt] + bp[nt] + gridf[o];
        }
      }
  }
}

extern "C" void kernel_launch(void* const* d_in, const int* in_sizes, int n_in,
                              void* d_out, int out_size, void* d_ws, size_t ws_size,
                              hipStream_t stream) {
  const float* m2g = (const float*)d_in[0];
  const float* grid = (const float*)d_in[1];
  const float* mesh = (const float*)d_in[2];
  const int* src = (const int*)d_in[3];
  const int* dst = (const int*)d_in[4];
  const float* We = (const float*)d_in[5];
  const float* Ws = (const float*)d_in[6];
  const float* Wd = (const float*)d_in[7];
  const float* b0 = (const float*)d_in[8];
  const float* W1e = (const float*)d_in[9];
  const float* b1e = (const float*)d_in[10];
  const float* ge = (const float*)d_in[11];
  const float* be = (const float*)d_in[12];
  const float* Wn0 = (const float*)d_in[13];
  const float* bn0 = (const float*)d_in[14];
  const float* Wn1 = (const float*)d_in[15];
  const float* bn1 = (const float*)d_in[16];
  const float* gn = (const float*)d_in[17];
  const float* bnv = (const float*)d_in[18];
  (void)in_sizes; (void)n_in; (void)out_size; (void)ws_size;

  char* ws = (char*)d_ws;
  float* agg = (float*)ws;                  // NG*128 f32 = 102,400,000 B
  size_t aggB = (size_t)NG * 128 * 4;
  size_t psB = (size_t)NM * 256;            // 10,486,272 B
  uint4* PS = (uint4*)(ws + aggB);
  uint4* PD = (uint4*)(ws + aggB + psB);    // 51,200,000 B

  prep_all<<<224, 256, 0, stream>>>(We, Ws, Wd, W1e, Wn0, Wn1);
  proj_kernel<<<1024, 256, 0, stream>>>(mesh, grid, PS, PD, agg);
  edge_kernel<<<1536, 256, 0, stream>>>(m2g, PS, PD, src, dst, b0, b1e, ge, be, agg);
  node_kernel<<<1536, 256, 0, stream>>>(grid, agg, bn0, bn1, gn, bnv, (float*)d_out);
}

// Round 7
// 1146.516 us; speedup vs baseline: 1.0893x; 1.0893x over previous
//
#include <hip/hip_runtime.h>
#include <math.h>

#define NM 40962
#define NG 200000
#define NE 600000

typedef unsigned short u16;
typedef unsigned int u32;
typedef __attribute__((ext_vector_type(8))) short short8;
typedef __attribute__((ext_vector_type(4))) float f32x4;

// Packed bf16 W^T blobs in static device memory.
#define OFF_WE 0
#define OFF_WS 16384
#define OFF_WD 32768
#define OFF_W1 49152
#define OFF_W0 65536
#define OFF_WN1 98304
__device__ u16 g_wp[114688];  // 224 KB

__device__ __forceinline__ u32 f2bf(float f) {
  u32 u = __float_as_uint(f);
  return (u + 0x7FFFu + ((u >> 16) & 1u)) >> 16;  // RNE
}
__device__ __forceinline__ float bfl(u32 h) { return __uint_as_float(h << 16); }
__device__ __forceinline__ float bsel(u32 w, int hiHalf) {
  return hiHalf ? __uint_as_float(w & 0xFFFF0000u) : __uint_as_float(w << 16);
}
__device__ __forceinline__ float silu_f(float x) { return x / (1.f + __expf(-x)); }

#define MFMA16(a, b, c) __builtin_amdgcn_mfma_f32_16x16x32_bf16(a, b, c, 0, 0, 0)

// pack 8 f32 into bf16 hi + bf16 lo-residual frags (fp32-accurate A)
__device__ __forceinline__ void pk8(const float4& a, const float4& b, short8& hi,
                                    short8& lo) {
  float f[8] = {a.x, a.y, a.z, a.w, b.x, b.y, b.z, b.w};
#pragma unroll
  for (int j = 0; j < 8; ++j) {
    u32 h = f2bf(f[j]);
    hi[j] = (short)h;
    lo[j] = (short)f2bf(f[j] - bfl(h));
  }
}

__device__ __forceinline__ void afrag_hl(const float* __restrict__ X, int row, int k0,
                                         short8& hi, short8& lo) {
  const float4* p = (const float4*)(X + (size_t)row * 128 + k0);
  pk8(p[0], p[1], hi, lo);
}

template <int K>
__device__ __forceinline__ short8 bfrag(const u16* __restrict__ Wp, int n, int k0) {
  return *(const short8*)(Wp + (size_t)n * K + k0);
}

// ---- fused prep: pack all 6 weight mats fp32 [K][128] -> g_wp bf16 [n][K] ----
__global__ void prep_all(const float* __restrict__ We, const float* __restrict__ Ws,
                         const float* __restrict__ Wd, const float* __restrict__ W1e,
                         const float* __restrict__ Wn0, const float* __restrict__ Wn1) {
  for (int i = blockIdx.x * blockDim.x + threadIdx.x; i < 114688;
       i += gridDim.x * blockDim.x) {
    const float* W;
    int loc, kb;
    if (i < 16384)       { W = We;  loc = i;         kb = 7; }
    else if (i < 32768)  { W = Ws;  loc = i - 16384; kb = 7; }
    else if (i < 49152)  { W = Wd;  loc = i - 32768; kb = 7; }
    else if (i < 65536)  { W = W1e; loc = i - 49152; kb = 7; }
    else if (i < 98304)  { W = Wn0; loc = i - 65536; kb = 8; }
    else                 { W = Wn1; loc = i - 98304; kb = 7; }
    int n = loc >> kb, k = loc & ((1 << kb) - 1);
    g_wp[i] = (u16)f2bf(W[(size_t)k * 128 + n]);
  }
}

// ---- fused proj (mesh->PS, grid->PD) M=32/wave, r5 structure (no prefetch:
//      keeps VGPR low for occupancy), agg zeroing folded in ----
__global__ __launch_bounds__(256) void proj_kernel(const float* __restrict__ mesh,
                                                   const float* __restrict__ gridf,
                                                   uint4* __restrict__ PS,
                                                   uint4* __restrict__ PD,
                                                   float* __restrict__ agg) {
  const int TM = (NM + 31) / 32;  // 1281
  const int TG = NG / 32;         // 6250
  const int lane = threadIdx.x & 63, wv = threadIdx.x >> 6;
  const int g = lane >> 4, c = lane & 15;
  const int nw = gridDim.x * 4;
  for (int t = blockIdx.x * 4 + wv; t < TM + TG; t += nw) {
    const float* X;
    const u16* Wp;
    uint4* O;
    int n0, nrows, zero;
    if (t < TM) { X = mesh;  Wp = g_wp + OFF_WS; O = PS; n0 = t * 32;        nrows = NM; zero = 0; }
    else        { X = gridf; Wp = g_wp + OFF_WD; O = PD; n0 = (t - TM) * 32; nrows = NG; zero = 1; }
    f32x4 acc[2][8];
#pragma unroll
    for (int mt = 0; mt < 2; ++mt)
#pragma unroll
      for (int nt = 0; nt < 8; ++nt) {
        f32x4 z = {0.f, 0.f, 0.f, 0.f};
        acc[mt][nt] = z;
      }
#pragma unroll
    for (int kt = 0; kt < 4; ++kt) {
      short8 ah[2], al[2];
#pragma unroll
      for (int mt = 0; mt < 2; ++mt) {
        int row = n0 + 16 * mt + c;
        if (row >= nrows) row = nrows - 1;  // tail clamp (loads only)
        afrag_hl(X, row, 32 * kt + 8 * g, ah[mt], al[mt]);
      }
#pragma unroll
      for (int nt = 0; nt < 8; ++nt) {
        short8 b = bfrag<128>(Wp, 16 * nt + c, 32 * kt + 8 * g);
#pragma unroll
        for (int mt = 0; mt < 2; ++mt) {
          acc[mt][nt] = MFMA16(ah[mt], b, acc[mt][nt]);
          acc[mt][nt] = MFMA16(al[mt], b, acc[mt][nt]);
        }
      }
    }
#pragma unroll
    for (int mt = 0; mt < 2; ++mt)
#pragma unroll
      for (int r = 0; r < 4; ++r) {
        int row = n0 + 16 * mt + 4 * g + r;
        if (row < nrows) {
          uint4 v;
          v.x = f2bf(acc[mt][0][r]) | (f2bf(acc[mt][1][r]) << 16);
          v.y = f2bf(acc[mt][2][r]) | (f2bf(acc[mt][3][r]) << 16);
          v.z = f2bf(acc[mt][4][r]) | (f2bf(acc[mt][5][r]) << 16);
          v.w = f2bf(acc[mt][6][r]) | (f2bf(acc[mt][7][r]) << 16);
          O[(size_t)row * 16 + c] = v;
          if (zero) {  // agg zeroing folded (replaces hipMemsetAsync)
            float4 z = {0.f, 0.f, 0.f, 0.f};
            float4* ap = (float4*)(agg + (size_t)row * 128 + c * 8);
            ap[0] = z;
            ap[1] = z;
          }
        }
      }
  }
}

// ---- edge (M=32/wave): r6 structure (cross-tile A-prefetch, deferred gathers)
//      + bijective XCD-chunk swizzle: dst sorted -> each XCD's PD window ~4MB = L2 ----
__global__ __launch_bounds__(256) void edge_kernel(
    const float* __restrict__ m2g, const uint4* __restrict__ PS,
    const uint4* __restrict__ PD, const int* __restrict__ src_idx,
    const int* __restrict__ dst_idx, const float* __restrict__ b0,
    const float* __restrict__ b1e, const float* __restrict__ ge,
    const float* __restrict__ be, float* __restrict__ agg) {
  const u16* WpE = g_wp + OFF_WE;
  const u16* Wp1 = g_wp + OFF_W1;
  __shared__ __align__(16) u16 hbh[4][32][128];  // hi plane, 32KB
  __shared__ __align__(16) u16 hbl[4][32][128];  // lo plane, 32KB
  const int lane = threadIdx.x & 63, wv = threadIdx.x >> 6;
  const int g = lane >> 4, c = lane & 15;
  // XCD-chunk swizzle (gridDim.x % 8 == 0 -> bijective): XCD x gets logical
  // blocks [x*cpx, (x+1)*cpx), i.e. contiguous edge windows per sweep.
  const int cpx = gridDim.x >> 3;
  const int swz = (blockIdx.x & 7) * cpx + (blockIdx.x >> 3);
  float b0p[8];
#pragma unroll
  for (int nt = 0; nt < 8; ++nt) b0p[nt] = b0[16 * nt + c];
  const int nw = gridDim.x * 4;
  const int T = NE / 32;
  int t0 = swz * 4 + wv;
  if (t0 >= T) return;
  float4 av[2][4][2];
  {  // prologue A
    const int e0 = t0 * 32;
#pragma unroll
    for (int mt = 0; mt < 2; ++mt)
#pragma unroll
      for (int kt = 0; kt < 4; ++kt) {
        const float4* p =
            (const float4*)(m2g + (size_t)(e0 + 16 * mt + c) * 128 + 32 * kt + 8 * g);
        av[mt][kt][0] = p[0];
        av[mt][kt][1] = p[1];
      }
  }
  for (int t = t0; t < T; t += nw) {
    const int e0 = t * 32;
    // gathers issued at top; consumed after GEMM1 (covered by MFMA)
    int dd[2][4];
    uint4 ps[2][4], pd[2][4];
#pragma unroll
    for (int mt = 0; mt < 2; ++mt)
#pragma unroll
      for (int r = 0; r < 4; ++r) {
        int e = e0 + 16 * mt + 4 * g + r;
        int s = src_idx[e];
        int d = dst_idx[e];
        dd[mt][r] = d;
        ps[mt][r] = PS[(size_t)s * 16 + c];
        pd[mt][r] = PD[(size_t)d * 16 + c];
      }
    // GEMM1 from zero (A already resident from prefetch)
    f32x4 acc[2][8];
#pragma unroll
    for (int mt = 0; mt < 2; ++mt)
#pragma unroll
      for (int nt = 0; nt < 8; ++nt) {
        f32x4 z = {0.f, 0.f, 0.f, 0.f};
        acc[mt][nt] = z;
      }
#pragma unroll
    for (int kt = 0; kt < 4; ++kt) {
      short8 ah[2], al[2];
#pragma unroll
      for (int mt = 0; mt < 2; ++mt) pk8(av[mt][kt][0], av[mt][kt][1], ah[mt], al[mt]);
#pragma unroll
      for (int nt = 0; nt < 8; ++nt) {
        short8 b = bfrag<128>(WpE, 16 * nt + c, 32 * kt + 8 * g);
#pragma unroll
        for (int mt = 0; mt < 2; ++mt) {
          acc[mt][nt] = MFMA16(ah[mt], b, acc[mt][nt]);
          acc[mt][nt] = MFMA16(al[mt], b, acc[mt][nt]);
        }
      }
    }
    {  // cross-tile A prefetch: issue now, consumed next iteration.
      int tn = t + nw;
      if (tn < T) {
        const int en = tn * 32;
#pragma unroll
        for (int mt = 0; mt < 2; ++mt)
#pragma unroll
          for (int kt = 0; kt < 4; ++kt) {
            const float4* p =
                (const float4*)(m2g + (size_t)(en + 16 * mt + c) * 128 + 32 * kt + 8 * g);
            av[mt][kt][0] = p[0];
            av[mt][kt][1] = p[1];
          }
      }
    }
    // deferred add of b0 + ps + pd (first consumption of the gathers)
#pragma unroll
    for (int mt = 0; mt < 2; ++mt)
#pragma unroll
      for (int nt = 0; nt < 8; ++nt)
#pragma unroll
        for (int r = 0; r < 4; ++r) {
          u32 pw = ((const u32*)&ps[mt][r])[nt >> 1];
          u32 qw = ((const u32*)&pd[mt][r])[nt >> 1];
          acc[mt][nt][r] += b0p[nt] + bsel(pw, nt & 1) + bsel(qw, nt & 1);
        }
    // silu -> hi/lo planes (XOR-swizzled)
#pragma unroll
    for (int mt = 0; mt < 2; ++mt)
#pragma unroll
      for (int r = 0; r < 4; ++r) {
        int row = 16 * mt + 4 * g + r;
        int sw = (row & 7) << 3;
#pragma unroll
        for (int nt = 0; nt < 8; ++nt) {
          float h = silu_f(acc[mt][nt][r]);
          u32 hb = f2bf(h);
          u32 lb = f2bf(h - bfl(hb));
          int idx = (16 * nt + c) ^ sw;
          hbh[wv][row][idx] = (u16)hb;
          hbl[wv][row][idx] = (u16)lb;
        }
      }
    // GEMM2: acc2 = b1e + h @ W1e (in-wave LDS transpose, no barrier needed)
    f32x4 acc2[2][8];
    {
      float b1p[8];
#pragma unroll
      for (int nt = 0; nt < 8; ++nt) b1p[nt] = b1e[16 * nt + c];
#pragma unroll
      for (int mt = 0; mt < 2; ++mt)
#pragma unroll
        for (int nt = 0; nt < 8; ++nt) {
          f32x4 a = {b1p[nt], b1p[nt], b1p[nt], b1p[nt]};
          acc2[mt][nt] = a;
        }
    }
#pragma unroll
    for (int kt = 0; kt < 4; ++kt) {
      short8 ah[2], al[2];
#pragma unroll
      for (int mt = 0; mt < 2; ++mt) {
        int row = 16 * mt + c;
        int idx = (32 * kt + 8 * g) ^ ((c & 7) << 3);
        ah[mt] = *(const short8*)&hbh[wv][row][idx];
        al[mt] = *(const short8*)&hbl[wv][row][idx];
      }
#pragma unroll
      for (int nt = 0; nt < 8; ++nt) {
        short8 b = bfrag<128>(Wp1, 16 * nt + c, 32 * kt + 8 * g);
#pragma unroll
        for (int mt = 0; mt < 2; ++mt) {
          acc2[mt][nt] = MFMA16(ah[mt], b, acc2[mt][nt]);
          acc2[mt][nt] = MFMA16(al[mt], b, acc2[mt][nt]);
        }
      }
    }
    // LN (16-lane shuffle reduce)
    float gep[8], bep[8];
#pragma unroll
    for (int nt = 0; nt < 8; ++nt) {
      gep[nt] = ge[16 * nt + c];
      bep[nt] = be[16 * nt + c];
    }
#pragma unroll
    for (int mt = 0; mt < 2; ++mt) {
#pragma unroll
      for (int r = 0; r < 4; ++r) {
        float sm = 0.f, sq = 0.f;
#pragma unroll
        for (int nt = 0; nt < 8; ++nt) {
          float v = acc2[mt][nt][r];
          sm += v;
          sq += v * v;
        }
#pragma unroll
        for (int m = 1; m < 16; m <<= 1) {
          sm += __shfl_xor(sm, m, 64);
          sq += __shfl_xor(sq, m, 64);
        }
        float mu = sm * (1.f / 128.f);
        float var = sq * (1.f / 128.f) - mu * mu;
        float rs = rsqrtf(var + 1e-5f);
#pragma unroll
        for (int nt = 0; nt < 8; ++nt)
          acc2[mt][nt][r] = (acc2[mt][nt][r] - mu) * rs * gep[nt] + bep[nt];
      }
      // dst-run-merged atomics (dst sorted -> adjacent duplicates merge)
#pragma unroll
      for (int nt = 0; nt < 8; ++nt) {
        float a = acc2[mt][nt][0];
        int dp = dd[mt][0];
#pragma unroll
        for (int r = 1; r < 4; ++r) {
          if (dd[mt][r] == dp) {
            a += acc2[mt][nt][r];
          } else {
            atomicAdd(agg + (size_t)dp * 128 + 16 * nt + c, a);
            a = acc2[mt][nt][r];
            dp = dd[mt][r];
          }
        }
        atomicAdd(agg + (size_t)dp * 128 + 16 * nt + c, a);
      }
    }
  }
}

// ---- node (fused A+B, M=32/wave, r5 structure — no prefetch: keeps VGPR
//      below the 256 cliff that killed r6's node) ----
__global__ __launch_bounds__(256) void node_kernel(
    const float* __restrict__ gridf, const float* __restrict__ agg,
    const float* __restrict__ bn0, const float* __restrict__ bn1,
    const float* __restrict__ gn, const float* __restrict__ bnv,
    float* __restrict__ out) {
  const u16* Wp0 = g_wp + OFF_W0;
  const u16* Wp1 = g_wp + OFF_WN1;
  __shared__ __align__(16) u16 nbuf[4][32][128];  // hn bf16, 32 KB/block
  const int lane = threadIdx.x & 63, wv = threadIdx.x >> 6;
  const int g = lane >> 4, c = lane & 15;
  float b0p[8], b1p[8];
#pragma unroll
  for (int nt = 0; nt < 8; ++nt) {
    b0p[nt] = bn0[16 * nt + c];
    b1p[nt] = bn1[16 * nt + c];
  }
  const int nw = gridDim.x * 4;
  for (int t = blockIdx.x * 4 + wv; t < NG / 32; t += nw) {
    const int n0 = t * 32;
    f32x4 acc[2][8];
#pragma unroll
    for (int mt = 0; mt < 2; ++mt)
#pragma unroll
      for (int nt = 0; nt < 8; ++nt) {
        f32x4 a = {b0p[nt], b0p[nt], b0p[nt], b0p[nt]};
        acc[mt][nt] = a;
      }
#pragma unroll
    for (int kt = 0; kt < 8; ++kt) {
      const float* src = (kt < 4) ? gridf : agg;
      int k0 = (kt & 3) * 32 + 8 * g;
      short8 ah[2], al[2];
#pragma unroll
      for (int mt = 0; mt < 2; ++mt) afrag_hl(src, n0 + 16 * mt + c, k0, ah[mt], al[mt]);
#pragma unroll
      for (int nt = 0; nt < 8; ++nt) {
        short8 b = bfrag<256>(Wp0, 16 * nt + c, 32 * kt + 8 * g);
#pragma unroll
        for (int mt = 0; mt < 2; ++mt) {
          acc[mt][nt] = MFMA16(ah[mt], b, acc[mt][nt]);
          acc[mt][nt] = MFMA16(al[mt], b, acc[mt][nt]);
        }
      }
    }
    // hn -> LDS (bf16)
#pragma unroll
    for (int mt = 0; mt < 2; ++mt)
#pragma unroll
      for (int r = 0; r < 4; ++r) {
        int row = 16 * mt + 4 * g + r;
        int sw = (row & 7) << 3;
#pragma unroll
        for (int nt = 0; nt < 8; ++nt)
          nbuf[wv][row][(16 * nt + c) ^ sw] = (u16)f2bf(silu_f(acc[mt][nt][r]));
      }
    f32x4 acc2[2][8];
#pragma unroll
    for (int mt = 0; mt < 2; ++mt)
#pragma unroll
      for (int nt = 0; nt < 8; ++nt) {
        f32x4 a = {b1p[nt], b1p[nt], b1p[nt], b1p[nt]};
        acc2[mt][nt] = a;
      }
#pragma unroll
    for (int kt = 0; kt < 4; ++kt) {
      short8 ah[2];
#pragma unroll
      for (int mt = 0; mt < 2; ++mt) {
        int row = 16 * mt + c;
        ah[mt] = *(const short8*)&nbuf[wv][row][(32 * kt + 8 * g) ^ ((c & 7) << 3)];
      }
#pragma unroll
      for (int nt = 0; nt < 8; ++nt) {
        short8 b = bfrag<128>(Wp1, 16 * nt + c, 32 * kt + 8 * g);
#pragma unroll
        for (int mt = 0; mt < 2; ++mt) acc2[mt][nt] = MFMA16(ah[mt], b, acc2[mt][nt]);
      }
    }
    // LN + residual + store
    float gp[8], bp[8];
#pragma unroll
    for (int nt = 0; nt < 8; ++nt) {
      gp[nt] = gn[16 * nt + c];
      bp[nt] = bnv[16 * nt + c];
    }
#pragma unroll
    for (int mt = 0; mt < 2; ++mt)
#pragma unroll
      for (int r = 0; r < 4; ++r) {
        float sm = 0.f, sq = 0.f;
#pragma unroll
        for (int nt = 0; nt < 8; ++nt) {
          float v = acc2[mt][nt][r];
          sm += v;
          sq += v * v;
        }
#pragma unroll
        for (int m = 1; m < 16; m <<= 1) {
          sm += __shfl_xor(sm, m, 64);
          sq += __shfl_xor(sq, m, 64);
        }
        float mu = sm * (1.f / 128.f);
        float var = sq * (1.f / 128.f) - mu * mu;
        float rs = rsqrtf(var + 1e-5f);
        int row = n0 + 16 * mt + 4 * g + r;
#pragma unroll
        for (int nt = 0; nt < 8; ++nt) {
          size_t o = (size_t)row * 128 + 16 * nt + c;
          out[o] = (acc2[mt][nt][r] - mu) * rs * gp[nt] + bp[nt] + gridf[o];
        }
      }
  }
}

extern "C" void kernel_launch(void* const* d_in, const int* in_sizes, int n_in,
                              void* d_out, int out_size, void* d_ws, size_t ws_size,
                              hipStream_t stream) {
  const float* m2g = (const float*)d_in[0];
  const float* grid = (const float*)d_in[1];
  const float* mesh = (const float*)d_in[2];
  const int* src = (const int*)d_in[3];
  const int* dst = (const int*)d_in[4];
  const float* We = (const float*)d_in[5];
  const float* Ws = (const float*)d_in[6];
  const float* Wd = (const float*)d_in[7];
  const float* b0 = (const float*)d_in[8];
  const float* W1e = (const float*)d_in[9];
  const float* b1e = (const float*)d_in[10];
  const float* ge = (const float*)d_in[11];
  const float* be = (const float*)d_in[12];
  const float* Wn0 = (const float*)d_in[13];
  const float* bn0 = (const float*)d_in[14];
  const float* Wn1 = (const float*)d_in[15];
  const float* bn1 = (const float*)d_in[16];
  const float* gn = (const float*)d_in[17];
  const float* bnv = (const float*)d_in[18];
  (void)in_sizes; (void)n_in; (void)out_size; (void)ws_size;

  char* ws = (char*)d_ws;
  float* agg = (float*)ws;                  // NG*128 f32 = 102,400,000 B
  size_t aggB = (size_t)NG * 128 * 4;
  size_t psB = (size_t)NM * 256;            // 10,486,272 B
  uint4* PS = (uint4*)(ws + aggB);
  uint4* PD = (uint4*)(ws + aggB + psB);    // 51,200,000 B

  prep_all<<<224, 256, 0, stream>>>(We, Ws, Wd, W1e, Wn0, Wn1);
  proj_kernel<<<1024, 256, 0, stream>>>(mesh, grid, PS, PD, agg);
  edge_kernel<<<1536, 256, 0, stream>>>(m2g, PS, PD, src, dst, b0, b1e, ge, be, agg);
  node_kernel<<<1536, 256, 0, stream>>>(grid, agg, bn0, bn1, gn, bnv, (float*)d_out);
}

// Round 8
// 1126.816 us; speedup vs baseline: 1.1083x; 1.0175x over previous
//
#include <hip/hip_runtime.h>
#include <math.h>

#define NM 40962
#define NG 200000
#define NE 600000

typedef unsigned short u16;
typedef unsigned int u32;
typedef __attribute__((ext_vector_type(8))) short short8;
typedef __attribute__((ext_vector_type(4))) float f32x4;
typedef __attribute__((ext_vector_type(4))) unsigned int u32x4;

// Packed bf16 W^T blobs in static device memory.
#define OFF_WE 0
#define OFF_WS 16384
#define OFF_WD 32768
#define OFF_W1 49152
#define OFF_W0 65536
#define OFF_WN1 98304
__device__ u16 g_wp[114688];  // 224 KB

// HW bf16 convert (RNE, same bits as the old +0x7FFF trick) — compiler lowers
// fptrunc f32->bf16 to v_cvt_pk_bf16_f32 on gfx950 (m240: casts beat hand-asm).
__device__ __forceinline__ u16 f2bfu(float f) {
  __bf16 h = (__bf16)f;
  return __builtin_bit_cast(u16, h);
}
__device__ __forceinline__ u32 pkbf(float a, float b) {
  return (u32)f2bfu(a) | ((u32)f2bfu(b) << 16);
}
__device__ __forceinline__ float bfl(u32 h) { return __uint_as_float(h << 16); }
__device__ __forceinline__ float bsel(u32 w, int hiHalf) {
  return hiHalf ? __uint_as_float(w & 0xFFFF0000u) : __uint_as_float(w << 16);
}
__device__ __forceinline__ float silu_f(float x) { return x / (1.f + __expf(-x)); }

#define MFMA16(a, b, c) __builtin_amdgcn_mfma_f32_16x16x32_bf16(a, b, c, 0, 0, 0)

// pack 8 f32 into bf16 hi + bf16 lo-residual frags (fp32-accurate A)
__device__ __forceinline__ void pk8(const float4& a, const float4& b, short8& hi,
                                    short8& lo) {
  float f[8] = {a.x, a.y, a.z, a.w, b.x, b.y, b.z, b.w};
  u32x4 h, l;
#pragma unroll
  for (int j = 0; j < 4; ++j) {
    u32 hw = pkbf(f[2 * j], f[2 * j + 1]);
    h[j] = hw;
    float r0 = f[2 * j] - __uint_as_float(hw << 16);
    float r1 = f[2 * j + 1] - __uint_as_float(hw & 0xFFFF0000u);
    l[j] = pkbf(r0, r1);
  }
  hi = __builtin_bit_cast(short8, h);
  lo = __builtin_bit_cast(short8, l);
}

__device__ __forceinline__ void afrag_hl(const float* __restrict__ X, int row, int k0,
                                         short8& hi, short8& lo) {
  const float4* p = (const float4*)(X + (size_t)row * 128 + k0);
  pk8(p[0], p[1], hi, lo);
}

template <int K>
__device__ __forceinline__ short8 bfrag(const u16* __restrict__ Wp, int n, int k0) {
  return *(const short8*)(Wp + (size_t)n * K + k0);
}

// ---- fused prep: pack all 6 weight mats fp32 [K][128] -> g_wp bf16 [n][K] ----
__global__ void prep_all(const float* __restrict__ We, const float* __restrict__ Ws,
                         const float* __restrict__ Wd, const float* __restrict__ W1e,
                         const float* __restrict__ Wn0, const float* __restrict__ Wn1) {
  for (int i = blockIdx.x * blockDim.x + threadIdx.x; i < 114688;
       i += gridDim.x * blockDim.x) {
    const float* W;
    int loc, kb;
    if (i < 16384)       { W = We;  loc = i;         kb = 7; }
    else if (i < 32768)  { W = Ws;  loc = i - 16384; kb = 7; }
    else if (i < 49152)  { W = Wd;  loc = i - 32768; kb = 7; }
    else if (i < 65536)  { W = W1e; loc = i - 49152; kb = 7; }
    else if (i < 98304)  { W = Wn0; loc = i - 65536; kb = 8; }
    else                 { W = Wn1; loc = i - 98304; kb = 7; }
    int n = loc >> kb, k = loc & ((1 << kb) - 1);
    g_wp[i] = f2bfu(W[(size_t)k * 128 + n]);
  }
}

// ---- fused proj (mesh->PS, grid->PD) M=32/wave, agg zeroing folded in ----
__global__ __launch_bounds__(256) void proj_kernel(const float* __restrict__ mesh,
                                                   const float* __restrict__ gridf,
                                                   uint4* __restrict__ PS,
                                                   uint4* __restrict__ PD,
                                                   float* __restrict__ agg) {
  const int TM = (NM + 31) / 32;  // 1281
  const int TG = NG / 32;         // 6250
  const int lane = threadIdx.x & 63, wv = threadIdx.x >> 6;
  const int g = lane >> 4, c = lane & 15;
  const int nw = gridDim.x * 4;
  for (int t = blockIdx.x * 4 + wv; t < TM + TG; t += nw) {
    const float* X;
    const u16* Wp;
    uint4* O;
    int n0, nrows, zero;
    if (t < TM) { X = mesh;  Wp = g_wp + OFF_WS; O = PS; n0 = t * 32;        nrows = NM; zero = 0; }
    else        { X = gridf; Wp = g_wp + OFF_WD; O = PD; n0 = (t - TM) * 32; nrows = NG; zero = 1; }
    f32x4 acc[2][8];
#pragma unroll
    for (int mt = 0; mt < 2; ++mt)
#pragma unroll
      for (int nt = 0; nt < 8; ++nt) {
        f32x4 z = {0.f, 0.f, 0.f, 0.f};
        acc[mt][nt] = z;
      }
#pragma unroll
    for (int kt = 0; kt < 4; ++kt) {
      short8 ah[2], al[2];
#pragma unroll
      for (int mt = 0; mt < 2; ++mt) {
        int row = n0 + 16 * mt + c;
        if (row >= nrows) row = nrows - 1;  // tail clamp (loads only)
        afrag_hl(X, row, 32 * kt + 8 * g, ah[mt], al[mt]);
      }
#pragma unroll
      for (int nt = 0; nt < 8; ++nt) {
        short8 b = bfrag<128>(Wp, 16 * nt + c, 32 * kt + 8 * g);
#pragma unroll
        for (int mt = 0; mt < 2; ++mt) {
          acc[mt][nt] = MFMA16(ah[mt], b, acc[mt][nt]);
          acc[mt][nt] = MFMA16(al[mt], b, acc[mt][nt]);
        }
      }
    }
#pragma unroll
    for (int mt = 0; mt < 2; ++mt)
#pragma unroll
      for (int r = 0; r < 4; ++r) {
        int row = n0 + 16 * mt + 4 * g + r;
        if (row < nrows) {
          uint4 v;
          v.x = pkbf(acc[mt][0][r], acc[mt][1][r]);
          v.y = pkbf(acc[mt][2][r], acc[mt][3][r]);
          v.z = pkbf(acc[mt][4][r], acc[mt][5][r]);
          v.w = pkbf(acc[mt][6][r], acc[mt][7][r]);
          O[(size_t)row * 16 + c] = v;
          if (zero) {  // agg zeroing folded (replaces hipMemsetAsync)
            float4 z = {0.f, 0.f, 0.f, 0.f};
            float4* ap = (float4*)(agg + (size_t)row * 128 + c * 8);
            ap[0] = z;
            ap[1] = z;
          }
        }
      }
  }
}

// ---- edge (M=32/wave): cross-tile A-prefetch, deferred gathers (r6 best, no swizzle) ----
__global__ __launch_bounds__(256) void edge_kernel(
    const float* __restrict__ m2g, const uint4* __restrict__ PS,
    const uint4* __restrict__ PD, const int* __restrict__ src_idx,
    const int* __restrict__ dst_idx, const float* __restrict__ b0,
    const float* __restrict__ b1e, const float* __restrict__ ge,
    const float* __restrict__ be, float* __restrict__ agg) {
  const u16* WpE = g_wp + OFF_WE;
  const u16* Wp1 = g_wp + OFF_W1;
  __shared__ __align__(16) u16 hbh[4][32][128];  // hi plane, 32KB
  __shared__ __align__(16) u16 hbl[4][32][128];  // lo plane, 32KB
  const int lane = threadIdx.x & 63, wv = threadIdx.x >> 6;
  const int g = lane >> 4, c = lane & 15;
  float b0p[8];
#pragma unroll
  for (int nt = 0; nt < 8; ++nt) b0p[nt] = b0[16 * nt + c];
  const int nw = gridDim.x * 4;
  const int T = NE / 32;
  int t0 = blockIdx.x * 4 + wv;
  if (t0 >= T) return;
  float4 av[2][4][2];
  {  // prologue A
    const int e0 = t0 * 32;
#pragma unroll
    for (int mt = 0; mt < 2; ++mt)
#pragma unroll
      for (int kt = 0; kt < 4; ++kt) {
        const float4* p =
            (const float4*)(m2g + (size_t)(e0 + 16 * mt + c) * 128 + 32 * kt + 8 * g);
        av[mt][kt][0] = p[0];
        av[mt][kt][1] = p[1];
      }
  }
  for (int t = t0; t < T; t += nw) {
    const int e0 = t * 32;
    // gathers issued at top; consumed after GEMM1 (covered by MFMA)
    int dd[2][4];
    uint4 ps[2][4], pd[2][4];
#pragma unroll
    for (int mt = 0; mt < 2; ++mt)
#pragma unroll
      for (int r = 0; r < 4; ++r) {
        int e = e0 + 16 * mt + 4 * g + r;
        int s = src_idx[e];
        int d = dst_idx[e];
        dd[mt][r] = d;
        ps[mt][r] = PS[(size_t)s * 16 + c];
        pd[mt][r] = PD[(size_t)d * 16 + c];
      }
    // GEMM1 from zero (A already resident from prefetch)
    f32x4 acc[2][8];
#pragma unroll
    for (int mt = 0; mt < 2; ++mt)
#pragma unroll
      for (int nt = 0; nt < 8; ++nt) {
        f32x4 z = {0.f, 0.f, 0.f, 0.f};
        acc[mt][nt] = z;
      }
#pragma unroll
    for (int kt = 0; kt < 4; ++kt) {
      short8 ah[2], al[2];
#pragma unroll
      for (int mt = 0; mt < 2; ++mt) pk8(av[mt][kt][0], av[mt][kt][1], ah[mt], al[mt]);
#pragma unroll
      for (int nt = 0; nt < 8; ++nt) {
        short8 b = bfrag<128>(WpE, 16 * nt + c, 32 * kt + 8 * g);
#pragma unroll
        for (int mt = 0; mt < 2; ++mt) {
          acc[mt][nt] = MFMA16(ah[mt], b, acc[mt][nt]);
          acc[mt][nt] = MFMA16(al[mt], b, acc[mt][nt]);
        }
      }
    }
    {  // cross-tile A prefetch: issue now, consumed next iteration.
      int tn = t + nw;
      if (tn < T) {
        const int en = tn * 32;
#pragma unroll
        for (int mt = 0; mt < 2; ++mt)
#pragma unroll
          for (int kt = 0; kt < 4; ++kt) {
            const float4* p =
                (const float4*)(m2g + (size_t)(en + 16 * mt + c) * 128 + 32 * kt + 8 * g);
            av[mt][kt][0] = p[0];
            av[mt][kt][1] = p[1];
          }
      }
    }
    // deferred add of b0 + ps + pd (first consumption of the gathers)
#pragma unroll
    for (int mt = 0; mt < 2; ++mt)
#pragma unroll
      for (int nt = 0; nt < 8; ++nt)
#pragma unroll
        for (int r = 0; r < 4; ++r) {
          u32 pw = ((const u32*)&ps[mt][r])[nt >> 1];
          u32 qw = ((const u32*)&pd[mt][r])[nt >> 1];
          acc[mt][nt][r] += b0p[nt] + bsel(pw, nt & 1) + bsel(qw, nt & 1);
        }
    // silu -> hi/lo planes (XOR-swizzled), pair-wise HW cvt
#pragma unroll
    for (int mt = 0; mt < 2; ++mt)
#pragma unroll
      for (int r = 0; r < 4; ++r) {
        int row = 16 * mt + 4 * g + r;
        int sw = (row & 7) << 3;
#pragma unroll
        for (int nt = 0; nt < 8; nt += 2) {
          float h0 = silu_f(acc[mt][nt][r]);
          float h1 = silu_f(acc[mt][nt + 1][r]);
          u32 hw = pkbf(h0, h1);
          float r0 = h0 - __uint_as_float(hw << 16);
          float r1 = h1 - __uint_as_float(hw & 0xFFFF0000u);
          u32 lw = pkbf(r0, r1);
          int i0 = (16 * nt + c) ^ sw;
          int i1 = (16 * nt + 16 + c) ^ sw;
          hbh[wv][row][i0] = (u16)hw;
          hbh[wv][row][i1] = (u16)(hw >> 16);
          hbl[wv][row][i0] = (u16)lw;
          hbl[wv][row][i1] = (u16)(lw >> 16);
        }
      }
    // GEMM2: acc2 = b1e + h @ W1e (in-wave LDS transpose, no barrier needed)
    f32x4 acc2[2][8];
    {
      float b1p[8];
#pragma unroll
      for (int nt = 0; nt < 8; ++nt) b1p[nt] = b1e[16 * nt + c];
#pragma unroll
      for (int mt = 0; mt < 2; ++mt)
#pragma unroll
        for (int nt = 0; nt < 8; ++nt) {
          f32x4 a = {b1p[nt], b1p[nt], b1p[nt], b1p[nt]};
          acc2[mt][nt] = a;
        }
    }
#pragma unroll
    for (int kt = 0; kt < 4; ++kt) {
      short8 ah[2], al[2];
#pragma unroll
      for (int mt = 0; mt < 2; ++mt) {
        int row = 16 * mt + c;
        int idx = (32 * kt + 8 * g) ^ ((c & 7) << 3);
        ah[mt] = *(const short8*)&hbh[wv][row][idx];
        al[mt] = *(const short8*)&hbl[wv][row][idx];
      }
#pragma unroll
      for (int nt = 0; nt < 8; ++nt) {
        short8 b = bfrag<128>(Wp1, 16 * nt + c, 32 * kt + 8 * g);
#pragma unroll
        for (int mt = 0; mt < 2; ++mt) {
          acc2[mt][nt] = MFMA16(ah[mt], b, acc2[mt][nt]);
          acc2[mt][nt] = MFMA16(al[mt], b, acc2[mt][nt]);
        }
      }
    }
    // LN (16-lane shuffle reduce)
    float gep[8], bep[8];
#pragma unroll
    for (int nt = 0; nt < 8; ++nt) {
      gep[nt] = ge[16 * nt + c];
      bep[nt] = be[16 * nt + c];
    }
#pragma unroll
    for (int mt = 0; mt < 2; ++mt) {
#pragma unroll
      for (int r = 0; r < 4; ++r) {
        float sm = 0.f, sq = 0.f;
#pragma unroll
        for (int nt = 0; nt < 8; ++nt) {
          float v = acc2[mt][nt][r];
          sm += v;
          sq += v * v;
        }
#pragma unroll
        for (int m = 1; m < 16; m <<= 1) {
          sm += __shfl_xor(sm, m, 64);
          sq += __shfl_xor(sq, m, 64);
        }
        float mu = sm * (1.f / 128.f);
        float var = sq * (1.f / 128.f) - mu * mu;
        float rs = rsqrtf(var + 1e-5f);
#pragma unroll
        for (int nt = 0; nt < 8; ++nt)
          acc2[mt][nt][r] = (acc2[mt][nt][r] - mu) * rs * gep[nt] + bep[nt];
      }
      // dst-run-merged atomics (dst sorted -> adjacent duplicates merge)
#pragma unroll
      for (int nt = 0; nt < 8; ++nt) {
        float a = acc2[mt][nt][0];
        int dp = dd[mt][0];
#pragma unroll
        for (int r = 1; r < 4; ++r) {
          if (dd[mt][r] == dp) {
            a += acc2[mt][nt][r];
          } else {
            atomicAdd(agg + (size_t)dp * 128 + 16 * nt + c, a);
            a = acc2[mt][nt][r];
            dp = dd[mt][r];
          }
        }
        atomicAdd(agg + (size_t)dp * 128 + 16 * nt + c, a);
      }
    }
  }
}

// ---- node (fused A+B, M=32/wave, no prefetch: stays under the VGPR cliff) ----
__global__ __launch_bounds__(256) void node_kernel(
    const float* __restrict__ gridf, const float* __restrict__ agg,
    const float* __restrict__ bn0, const float* __restrict__ bn1,
    const float* __restrict__ gn, const float* __restrict__ bnv,
    float* __restrict__ out) {
  const u16* Wp0 = g_wp + OFF_W0;
  const u16* Wp1 = g_wp + OFF_WN1;
  __shared__ __align__(16) u16 nbuf[4][32][128];  // hn bf16, 32 KB/block
  const int lane = threadIdx.x & 63, wv = threadIdx.x >> 6;
  const int g = lane >> 4, c = lane & 15;
  float b0p[8], b1p[8];
#pragma unroll
  for (int nt = 0; nt < 8; ++nt) {
    b0p[nt] = bn0[16 * nt + c];
    b1p[nt] = bn1[16 * nt + c];
  }
  const int nw = gridDim.x * 4;
  for (int t = blockIdx.x * 4 + wv; t < NG / 32; t += nw) {
    const int n0 = t * 32;
    f32x4 acc[2][8];
#pragma unroll
    for (int mt = 0; mt < 2; ++mt)
#pragma unroll
      for (int nt = 0; nt < 8; ++nt) {
        f32x4 a = {b0p[nt], b0p[nt], b0p[nt], b0p[nt]};
        acc[mt][nt] = a;
      }
#pragma unroll
    for (int kt = 0; kt < 8; ++kt) {
      const float* src = (kt < 4) ? gridf : agg;
      int k0 = (kt & 3) * 32 + 8 * g;
      short8 ah[2], al[2];
#pragma unroll
      for (int mt = 0; mt < 2; ++mt) afrag_hl(src, n0 + 16 * mt + c, k0, ah[mt], al[mt]);
#pragma unroll
      for (int nt = 0; nt < 8; ++nt) {
        short8 b = bfrag<256>(Wp0, 16 * nt + c, 32 * kt + 8 * g);
#pragma unroll
        for (int mt = 0; mt < 2; ++mt) {
          acc[mt][nt] = MFMA16(ah[mt], b, acc[mt][nt]);
          acc[mt][nt] = MFMA16(al[mt], b, acc[mt][nt]);
        }
      }
    }
    // hn -> LDS (bf16, pair-wise HW cvt)
#pragma unroll
    for (int mt = 0; mt < 2; ++mt)
#pragma unroll
      for (int r = 0; r < 4; ++r) {
        int row = 16 * mt + 4 * g + r;
        int sw = (row & 7) << 3;
#pragma unroll
        for (int nt = 0; nt < 8; nt += 2) {
          u32 hw = pkbf(silu_f(acc[mt][nt][r]), silu_f(acc[mt][nt + 1][r]));
          nbuf[wv][row][(16 * nt + c) ^ sw] = (u16)hw;
          nbuf[wv][row][(16 * nt + 16 + c) ^ sw] = (u16)(hw >> 16);
        }
      }
    f32x4 acc2[2][8];
#pragma unroll
    for (int mt = 0; mt < 2; ++mt)
#pragma unroll
      for (int nt = 0; nt < 8; ++nt) {
        f32x4 a = {b1p[nt], b1p[nt], b1p[nt], b1p[nt]};
        acc2[mt][nt] = a;
      }
#pragma unroll
    for (int kt = 0; kt < 4; ++kt) {
      short8 ah[2];
#pragma unroll
      for (int mt = 0; mt < 2; ++mt) {
        int row = 16 * mt + c;
        ah[mt] = *(const short8*)&nbuf[wv][row][(32 * kt + 8 * g) ^ ((c & 7) << 3)];
      }
#pragma unroll
      for (int nt = 0; nt < 8; ++nt) {
        short8 b = bfrag<128>(Wp1, 16 * nt + c, 32 * kt + 8 * g);
#pragma unroll
        for (int mt = 0; mt < 2; ++mt) acc2[mt][nt] = MFMA16(ah[mt], b, acc2[mt][nt]);
      }
    }
    // LN + residual + store
    float gp[8], bp[8];
#pragma unroll
    for (int nt = 0; nt < 8; ++nt) {
      gp[nt] = gn[16 * nt + c];
      bp[nt] = bnv[16 * nt + c];
    }
#pragma unroll
    for (int mt = 0; mt < 2; ++mt)
#pragma unroll
      for (int r = 0; r < 4; ++r) {
        float sm = 0.f, sq = 0.f;
#pragma unroll
        for (int nt = 0; nt < 8; ++nt) {
          float v = acc2[mt][nt][r];
          sm += v;
          sq += v * v;
        }
#pragma unroll
        for (int m = 1; m < 16; m <<= 1) {
          sm += __shfl_xor(sm, m, 64);
          sq += __shfl_xor(sq, m, 64);
        }
        float mu = sm * (1.f / 128.f);
        float var = sq * (1.f / 128.f) - mu * mu;
        float rs = rsqrtf(var + 1e-5f);
        int row = n0 + 16 * mt + 4 * g + r;
#pragma unroll
        for (int nt = 0; nt < 8; ++nt) {
          size_t o = (size_t)row * 128 + 16 * nt + c;
          out[o] = (acc2[mt][nt][r] - mu) * rs * gp[nt] + bp[nt] + gridf[o];
        }
      }
  }
}

extern "C" void kernel_launch(void* const* d_in, const int* in_sizes, int n_in,
                              void* d_out, int out_size, void* d_ws, size_t ws_size,
                              hipStream_t stream) {
  const float* m2g = (const float*)d_in[0];
  const float* grid = (const float*)d_in[1];
  const float* mesh = (const float*)d_in[2];
  const int* src = (const int*)d_in[3];
  const int* dst = (const int*)d_in[4];
  const float* We = (const float*)d_in[5];
  const float* Ws = (const float*)d_in[6];
  const float* Wd = (const float*)d_in[7];
  const float* b0 = (const float*)d_in[8];
  const float* W1e = (const float*)d_in[9];
  const float* b1e = (const float*)d_in[10];
  const float* ge = (const float*)d_in[11];
  const float* be = (const float*)d_in[12];
  const float* Wn0 = (const float*)d_in[13];
  const float* bn0 = (const float*)d_in[14];
  const float* Wn1 = (const float*)d_in[15];
  const float* bn1 = (const float*)d_in[16];
  const float* gn = (const float*)d_in[17];
  const float* bnv = (const float*)d_in[18];
  (void)in_sizes; (void)n_in; (void)out_size; (void)ws_size;

  char* ws = (char*)d_ws;
  float* agg = (float*)ws;                  // NG*128 f32 = 102,400,000 B
  size_t aggB = (size_t)NG * 128 * 4;
  size_t psB = (size_t)NM * 256;            // 10,486,272 B
  uint4* PS = (uint4*)(ws + aggB);
  uint4* PD = (uint4*)(ws + aggB + psB);    // 51,200,000 B

  prep_all<<<224, 256, 0, stream>>>(We, Ws, Wd, W1e, Wn0, Wn1);
  proj_kernel<<<1024, 256, 0, stream>>>(mesh, grid, PS, PD, agg);
  edge_kernel<<<1536, 256, 0, stream>>>(m2g, PS, PD, src, dst, b0, b1e, ge, be, agg);
  node_kernel<<<1536, 256, 0, stream>>>(grid, agg, bn0, bn1, gn, bnv, (float*)d_out);
}